// Round 5
// baseline (170.438 us; speedup 1.0000x reference)
//
#include <hip/hip_runtime.h>
#include <hip/hip_bf16.h>

#define IN_PNN  4096
#define OUT_PNN 2048
#define MM      16
#define ICC     32
#define OCC     64
#define NP      2          // output points per block (16 GEMM rows)
#define NT      16         // k-chunks of 64 (K = 1024)
#define REP     5          // diagnostic: main loop x5, acc scaled by 1/5

typedef __attribute__((ext_vector_type(8))) short short8;
typedef __attribute__((ext_vector_type(4))) float f32x4;

// ws layout:
//   [0, 131072)            ktb bf16 [64 o][1024 k']   k' = t*64 + 2*i + wl  (w = 2t+wl)
//   [131072, 139264)       wrt f32  [32 i][64 o]
//   [262144, 4456448)      wwm f32  [2048 p][16 t][16 m][2 wl]  masked w_weights

__global__ __launch_bounds__(256) void prep_kernel(const float* __restrict__ weights,
                                                   const float* __restrict__ wres,
                                                   const float* __restrict__ ww,
                                                   const int*   __restrict__ nid,
                                                   __hip_bfloat16* __restrict__ ktb,
                                                   float* __restrict__ wrt,
                                                   float* __restrict__ wwm) {
  int t = blockIdx.x * 256 + threadIdx.x;      // 0 .. 1048575
  {
    int p = t >> 9, j = t & 511;
    int tt = j >> 5, m = (j >> 1) & 15, wl = j & 1;
    int id = nid[p * MM + m];
    wwm[t] = (id != IN_PNN) ? ww[p * 512 + m * 32 + 2 * tt + wl] : 0.f;
  }
  if (t < 64 * 1024) {
    int o = t >> 10, kp = t & 1023;
    int tt = kp >> 6, r6 = kp & 63, i = r6 >> 1, wl = r6 & 1;
    int w = 2 * tt + wl;
    ktb[t] = __float2bfloat16(weights[w * (OCC * ICC) + o * ICC + i]);
  }
  if (t < ICC * OCC) {
    int i = t >> 6, o = t & 63;
    wrt[t] = wres[o * ICC + i];
  }
}

__global__ __launch_bounds__(256, 4) void fused5_kernel(
    const float* __restrict__ in_pc,   // [8][4096][32]
    const float* __restrict__ bias,    // [64]
    const float* __restrict__ praw,    // [2048][16]
    const int*   __restrict__ nid,     // [2048][16]
    const char*  __restrict__ ktb,     // bf16 [64][1024] (k'-permuted)
    const float* __restrict__ wrt,     // [32][64]
    const float* __restrict__ wwm,     // [2048][512]
    float*       __restrict__ out) {   // [8][2048][64]

  __shared__ float s_wrt[ICC * OCC];                    // 8 KB
  __shared__ float s_praw[NP][MM];
  __shared__ float s_q[16][33];                         // [r][i]
  __shared__ __align__(16) unsigned char s_A[2][2048];  // dbuf A-tile [16 r][128 B], XOR-swizzled
  __shared__ float s_acc[16][68];

  const int tid   = threadIdx.x;
  const int pbase = blockIdx.x * NP;
  const int ph = tid >> 7;          // 0..1 (wave-uniform)
  const int bg = (tid >> 5) & 3;    // 0..3
  const int i  = tid & 31;          // channel

  // ---- gather neighbors (coalesced 128B rows per half-wave) ----
  const int prow = (pbase + ph) * MM;
  float nbr[2][MM];
#pragma unroll
  for (int d = 0; d < 2; ++d) {
    const float* base = in_pc + (size_t)(bg + 4 * d) * (IN_PNN * ICC) + i;
#pragma unroll
    for (int m = 0; m < MM; ++m) {
      int id = nid[prow + m];
      int idc = (id < IN_PNN) ? id : 0;      // masked via wwm / s_praw
      nbr[d][m] = base[(size_t)idc * ICC];
    }
  }

  // ---- stage wrt + masked |praw| ----
  for (int e = tid; e < ICC * OCC; e += 256) s_wrt[e] = wrt[e];
  if (tid < NP * MM) {
    int pp = tid >> 4, m = tid & 15;
    int id = nid[(pbase + pp) * MM + m];
    s_praw[pp][m] = (id != IN_PNN) ? fabsf(praw[(pbase + pp) * MM + m]) : 0.f;
  }
  __syncthreads();

  // ---- residual q ----
  {
    float s = 1e-8f;
#pragma unroll
    for (int m = 0; m < MM; ++m) s += s_praw[ph][m];
    float pv = 1.f / s;
#pragma unroll
    for (int d = 0; d < 2; ++d) {
      float q = 0.f;
#pragma unroll
      for (int m = 0; m < MM; ++m) q = fmaf(s_praw[ph][m], nbr[d][m], q);
      s_q[ph * 8 + bg + 4 * d][i] = q * pv;
    }
  }

  // ---- GEMM setup: 4 waves = 4 o-tiles (16 rows x 64 cols) ----
  const int l  = tid & 63;
  const int wc = tid >> 6;                 // 0..3
  const int ph_u = __builtin_amdgcn_readfirstlane(ph);
  const float4* __restrict__ wwp4 =
      (const float4*)(wwm + (size_t)(pbase + ph_u) * 512);   // SGPR-uniform

  const char* Bbase = ktb + ((size_t)(wc * 16 + (l & 15)) * 1024 + (l >> 4) * 8) * 2;
  const int rA = ph * 8 + bg;
  int wby[2];
#pragma unroll
  for (int d = 0; d < 2; ++d) {
    int r = rA + 4 * d;
    wby[d] = r * 128 + (((i >> 2) ^ (r & 7)) << 4) + ((i & 3) << 2);
  }
  const int arow = l & 15;
  const int rby0 = arow * 128 + ((((l >> 4) + 0) ^ (arow & 7)) << 4);
  const int rby1 = arow * 128 + ((((l >> 4) + 4) ^ (arow & 7)) << 4);

  f32x4 acc = {0.f, 0.f, 0.f, 0.f};

  for (int rep = 0; rep < REP; ++rep) {
    uint4 Bc0 = *(const uint4*)(Bbase);
    uint4 Bc1 = *(const uint4*)(Bbase + 64);
#pragma unroll
    for (int t = 0; t < NT; ++t) {
      // coefficients: 8 x float4 via SGPR-uniform pointer (s_load_dwordx4)
      float h00 = 0.f, h01 = 0.f, h10 = 0.f, h11 = 0.f;
#pragma unroll
      for (int c = 0; c < 8; ++c) {
        float4 cf = wwp4[t * 8 + c];       // m = 2c (x=wl0,y=wl1), m = 2c+1 (z,w)
        float n0 = nbr[0][2 * c], n1 = nbr[0][2 * c + 1];
        float u0 = nbr[1][2 * c], u1 = nbr[1][2 * c + 1];
        h00 = fmaf(cf.x, n0, h00); h00 = fmaf(cf.z, n1, h00);
        h01 = fmaf(cf.y, n0, h01); h01 = fmaf(cf.w, n1, h01);
        h10 = fmaf(cf.x, u0, h10); h10 = fmaf(cf.z, u1, h10);
        h11 = fmaf(cf.y, u0, h11); h11 = fmaf(cf.w, u1, h11);
      }
      {
        unsigned char* Abuf = s_A[t & 1];
        __hip_bfloat16 c0 = __float2bfloat16(h00), c1 = __float2bfloat16(h01);
        __hip_bfloat16 c2 = __float2bfloat16(h10), c3 = __float2bfloat16(h11);
        unsigned int pk0 = (unsigned int)*(unsigned short*)&c0 |
                           ((unsigned int)*(unsigned short*)&c1 << 16);
        unsigned int pk1 = (unsigned int)*(unsigned short*)&c2 |
                           ((unsigned int)*(unsigned short*)&c3 << 16);
        *(unsigned int*)(Abuf + wby[0]) = pk0;
        *(unsigned int*)(Abuf + wby[1]) = pk1;
      }
      uint4 Bn0, Bn1;
      if (t < NT - 1) {
        Bn0 = *(const uint4*)(Bbase + (size_t)(t + 1) * 128);
        Bn1 = *(const uint4*)(Bbase + (size_t)(t + 1) * 128 + 64);
      }
      __syncthreads();                     // A(t) visible; dbuf => safe (see R3/R4)
      {
        const unsigned char* Ab = s_A[t & 1];
        short8 a0 = *(const short8*)(Ab + rby0);
        short8 a1 = *(const short8*)(Ab + rby1);
        acc = __builtin_amdgcn_mfma_f32_16x16x32_bf16(a0, *(short8*)&Bc0, acc, 0, 0, 0);
        acc = __builtin_amdgcn_mfma_f32_16x16x32_bf16(a1, *(short8*)&Bc1, acc, 0, 0, 0);
      }
      if (t < NT - 1) { Bc0 = Bn0; Bc1 = Bn1; }
    }
  }
  // REP identical accumulation passes -> scale once (keeps all MFMAs live; no DCE)
  acc[0] *= (1.f / REP); acc[1] *= (1.f / REP);
  acc[2] *= (1.f / REP); acc[3] *= (1.f / REP);

  // ---- epilogue (once) ----
  {
    int row0 = (l >> 4) * 4;
    int o    = wc * 16 + (l & 15);
#pragma unroll
    for (int j = 0; j < 4; ++j) s_acc[row0 + j][o] = acc[j];  // C: col=l&15, row=(l>>4)*4+j
  }
  __syncthreads();
  {
    int r  = tid >> 4;            // 0..15
    int og = (tid & 15) * 4;
    float4 a  = *(const float4*)&s_acc[r][og];
    float4 rs = {0.f, 0.f, 0.f, 0.f};
#pragma unroll
    for (int i2 = 0; i2 < ICC; ++i2) {
      float  qv  = s_q[r][i2];
      float4 wv4 = *(const float4*)&s_wrt[i2 * 64 + og];
      rs.x = fmaf(wv4.x, qv, rs.x);
      rs.y = fmaf(wv4.y, qv, rs.y);
      rs.z = fmaf(wv4.z, qv, rs.z);
      rs.w = fmaf(wv4.w, qv, rs.w);
    }
    float4 bz = *(const float4*)&bias[og];
    float c0 = a.x + bz.x, c1 = a.y + bz.y, c2 = a.z + bz.z, c3 = a.w + bz.w;
    c0 = (c0 > 0.f) ? c0 : (__expf(c0) - 1.f);
    c1 = (c1 > 0.f) ? c1 : (__expf(c1) - 1.f);
    c2 = (c2 > 0.f) ? c2 : (__expf(c2) - 1.f);
    c3 = (c3 > 0.f) ? c3 : (__expf(c3) - 1.f);
    const float rmix = 0.70710678118654752f;
    float4 o4;
    o4.x = rmix * (c0 + rs.x);
    o4.y = rmix * (c1 + rs.y);
    o4.z = rmix * (c2 + rs.z);
    o4.w = rmix * (c3 + rs.w);
    int b = r & 7, p = pbase + (r >> 3);
    *(float4*)&out[((size_t)b * OUT_PNN + p) * OCC + og] = o4;
  }
}

extern "C" void kernel_launch(void* const* d_in, const int* in_sizes, int n_in,
                              void* d_out, int out_size, void* d_ws, size_t ws_size,
                              hipStream_t stream) {
  const float* in_pc   = (const float*)d_in[0];
  const float* weights = (const float*)d_in[1];
  const float* bias    = (const float*)d_in[2];
  const float* w_w     = (const float*)d_in[3];
  const float* praw    = (const float*)d_in[4];
  const float* wres    = (const float*)d_in[5];
  const int*   nid     = (const int*)d_in[6];
  float* outp = (float*)d_out;

  __hip_bfloat16* ktb = (__hip_bfloat16*)d_ws;
  float* wrt = (float*)((char*)d_ws + 131072);
  float* wwm = (float*)((char*)d_ws + 262144);

  prep_kernel<<<4096, 256, 0, stream>>>(weights, wres, w_w, nid, ktb, wrt, wwm);
  fused5_kernel<<<OUT_PNN / NP, 256, 0, stream>>>(in_pc, bias, praw, nid,
                                                  (const char*)ktb, wrt, wwm, outp);
}

// Round 6
// 95.820 us; speedup vs baseline: 1.7787x; 1.7787x over previous
//
#include <hip/hip_runtime.h>
#include <hip/hip_bf16.h>

#define IN_PNN  4096
#define OUT_PNN 2048
#define MM      16
#define ICC     32
#define OCC     64
#define NP      2          // output points per block (16 GEMM rows)
#define NT      16         // k-chunks of 64 (K = 1024)

typedef __attribute__((ext_vector_type(8))) short short8;
typedef __attribute__((ext_vector_type(4))) float f32x4;

// ws layout:
//   [0, 131072)            ktb bf16 [64 o][1024 k']   k' = t*64 + 2*i + wl  (w = 2t+wl)
//   [131072, 139264)       wrt f32  [32 i][64 o]
//   [262144, 4456448)      wwm f32  [2048 p][16 t][16 m][2 wl]  masked w_weights

__global__ __launch_bounds__(256) void prep_kernel(const float* __restrict__ weights,
                                                   const float* __restrict__ wres,
                                                   const float* __restrict__ ww,
                                                   const int*   __restrict__ nid,
                                                   __hip_bfloat16* __restrict__ ktb,
                                                   float* __restrict__ wrt,
                                                   float* __restrict__ wwm) {
  int t = blockIdx.x * 256 + threadIdx.x;      // 0 .. 1048575
  {
    int p = t >> 9, j = t & 511;
    int tt = j >> 5, m = (j >> 1) & 15, wl = j & 1;
    int id = nid[p * MM + m];
    wwm[t] = (id != IN_PNN) ? ww[p * 512 + m * 32 + 2 * tt + wl] : 0.f;
  }
  if (t < 64 * 1024) {
    int o = t >> 10, kp = t & 1023;
    int tt = kp >> 6, r6 = kp & 63, i = r6 >> 1, wl = r6 & 1;
    int w = 2 * tt + wl;
    ktb[t] = __float2bfloat16(weights[w * (OCC * ICC) + o * ICC + i]);
  }
  if (t < ICC * OCC) {
    int i = t >> 6, o = t & 63;
    wrt[t] = wres[o * ICC + i];
  }
}

__global__ __launch_bounds__(512, 4) void fused6_kernel(
    const float* __restrict__ in_pc,   // [8][4096][32]
    const float* __restrict__ bias,    // [64]
    const float* __restrict__ praw,    // [2048][16]
    const int*   __restrict__ nid,     // [2048][16]
    const char*  __restrict__ ktb,     // bf16 [64][1024] (k'-permuted)
    const float* __restrict__ wrt,     // [32][64]
    const float* __restrict__ wwm,     // [2048][512]
    float*       __restrict__ out) {   // [8][2048][64]

  __shared__ float s_wrt[ICC * OCC];                    // 8 KB
  __shared__ float s_praw[NP][MM];
  __shared__ float s_q[16][33];                         // [r][i]
  __shared__ __align__(16) unsigned char s_A[2][2048];  // dbuf A-tile [16 r][128 B], swizzled
  __shared__ float s_acc[2][16][68];                    // per-K-half partial C

  const int tid   = threadIdx.x;
  const int pbase = blockIdx.x * NP;
  const int ph = tid >> 8;          // 0..1 (wave-uniform)
  const int b  = (tid >> 5) & 7;    // batch (ONE per thread -> nbr[16] only)
  const int i  = tid & 31;          // channel

  // ---- gather neighbors (each 32-lane group reads coalesced 128B rows) ----
  const int prow = (pbase + ph) * MM;
  float nbr[MM];
  {
    const float* base = in_pc + (size_t)b * (IN_PNN * ICC) + i;
#pragma unroll
    for (int m = 0; m < MM; ++m) {
      int id = nid[prow + m];                // wave-uniform -> s_load
      int idc = (id < IN_PNN) ? id : 0;      // masked via wwm / s_praw
      nbr[m] = base[(size_t)idc * ICC];
    }
  }

  // ---- stage wrt + masked |praw| ----
  for (int e = tid; e < ICC * OCC; e += 512) s_wrt[e] = wrt[e];
  if (tid < NP * MM) {
    int pp = tid >> 4, m = tid & 15;
    int id = nid[(pbase + pp) * MM + m];
    s_praw[pp][m] = (id != IN_PNN) ? fabsf(praw[(pbase + pp) * MM + m]) : 0.f;
  }
  __syncthreads();

  // ---- residual q ----
  {
    float s = 1e-8f;
#pragma unroll
    for (int m = 0; m < MM; ++m) s += s_praw[ph][m];
    float pv = 1.f / s;
    float q = 0.f;
#pragma unroll
    for (int m = 0; m < MM; ++m) q = fmaf(s_praw[ph][m], nbr[m], q);
    s_q[ph * 8 + b][i] = q * pv;
  }

  // ---- GEMM setup: 8 waves = {K-parity ks} x {o-tile wc} ----
  const int l  = tid & 63;
  const int wv = tid >> 6;
  const int wc = wv & 3;                 // o-tile
  const int ks = wv >> 2;                // K parity (== ph); consumes buf[ks] only
  const int ph_u = __builtin_amdgcn_readfirstlane(ph);
  const float4* __restrict__ wwp4 =
      (const float4*)(wwm + (size_t)(pbase + ph_u) * 512);   // SGPR-uniform

  const char* Bbase = ktb + ((size_t)(wc * 16 + (l & 15)) * 1024 + (l >> 4) * 8) * 2;
  const int rA  = ph * 8 + b;            // A row owned by this thread
  const int wby = rA * 128 + (((i >> 2) ^ (rA & 7)) << 4) + ((i & 3) << 2);
  const int arow = l & 15;
  const int rby0 = arow * 128 + ((((l >> 4) + 0) ^ (arow & 7)) << 4);
  const int rby1 = arow * 128 + ((((l >> 4) + 4) ^ (arow & 7)) << 4);

  f32x4 acc = {0.f, 0.f, 0.f, 0.f};
  uint4 Bc0 = *(const uint4*)(Bbase + (size_t)ks * 128);
  uint4 Bc1 = *(const uint4*)(Bbase + (size_t)ks * 128 + 64);

#pragma unroll
  for (int t = 0; t < NT; ++t) {
    // h for w-pair {2t, 2t+1}, one b: 32 FMA off SGPR-uniform coefficients
    float h0 = 0.f, h1 = 0.f;
#pragma unroll
    for (int c = 0; c < 8; ++c) {
      float4 cf = wwp4[t * 8 + c];       // (m=2c: x=wl0,y=wl1) (m=2c+1: z,w)
      float n0 = nbr[2 * c], n1 = nbr[2 * c + 1];
      h0 = fmaf(cf.x, n0, h0); h0 = fmaf(cf.z, n1, h0);
      h1 = fmaf(cf.y, n0, h1); h1 = fmaf(cf.w, n1, h1);
    }
    {
      unsigned char* Abuf = s_A[t & 1];
      __hip_bfloat16 c0 = __float2bfloat16(h0), c1 = __float2bfloat16(h1);
      unsigned int pk = (unsigned int)*(unsigned short*)&c0 |
                        ((unsigned int)*(unsigned short*)&c1 << 16);
      *(unsigned int*)(Abuf + wby) = pk;   // conflict-free b32 (banks all distinct)
    }
    __syncthreads();                       // A(t) visible; wave (ks) reads only buf[ks]
    if ((t & 1) == ks) {
      const unsigned char* Ab = s_A[ks];
      short8 a0 = *(const short8*)(Ab + rby0);
      short8 a1 = *(const short8*)(Ab + rby1);
      uint4 Bn0, Bn1;
      if (t + 2 < NT) {                    // prefetch this wave's next chunk
        Bn0 = *(const uint4*)(Bbase + (size_t)(t + 2) * 128);
        Bn1 = *(const uint4*)(Bbase + (size_t)(t + 2) * 128 + 64);
      }
      acc = __builtin_amdgcn_mfma_f32_16x16x32_bf16(a0, *(short8*)&Bc0, acc, 0, 0, 0);
      acc = __builtin_amdgcn_mfma_f32_16x16x32_bf16(a1, *(short8*)&Bc1, acc, 0, 0, 0);
      if (t + 2 < NT) { Bc0 = Bn0; Bc1 = Bn1; }
    }
  }

  // ---- epilogue: sum K-halves, residual + bias + ELU + mix ----
  {
    int row0 = (l >> 4) * 4;
    int o    = wc * 16 + (l & 15);
#pragma unroll
    for (int j = 0; j < 4; ++j) s_acc[ks][row0 + j][o] = acc[j];  // C: col=l&15, row=(l>>4)*4+j
  }
  __syncthreads();
  if (tid < 256) {
    int r  = tid >> 4;            // 0..15
    int og = (tid & 15) * 4;
    float4 a0 = *(const float4*)&s_acc[0][r][og];
    float4 a1 = *(const float4*)&s_acc[1][r][og];
    float4 rs = {0.f, 0.f, 0.f, 0.f};
#pragma unroll
    for (int i2 = 0; i2 < ICC; ++i2) {
      float  qv  = s_q[r][i2];
      float4 wv4 = *(const float4*)&s_wrt[i2 * 64 + og];
      rs.x = fmaf(wv4.x, qv, rs.x);
      rs.y = fmaf(wv4.y, qv, rs.y);
      rs.z = fmaf(wv4.z, qv, rs.z);
      rs.w = fmaf(wv4.w, qv, rs.w);
    }
    float4 bz = *(const float4*)&bias[og];
    float c0 = a0.x + a1.x + bz.x, c1 = a0.y + a1.y + bz.y;
    float c2 = a0.z + a1.z + bz.z, c3 = a0.w + a1.w + bz.w;
    c0 = (c0 > 0.f) ? c0 : (__expf(c0) - 1.f);
    c1 = (c1 > 0.f) ? c1 : (__expf(c1) - 1.f);
    c2 = (c2 > 0.f) ? c2 : (__expf(c2) - 1.f);
    c3 = (c3 > 0.f) ? c3 : (__expf(c3) - 1.f);
    const float rmix = 0.70710678118654752f;
    float4 o4;
    o4.x = rmix * (c0 + rs.x);
    o4.y = rmix * (c1 + rs.y);
    o4.z = rmix * (c2 + rs.z);
    o4.w = rmix * (c3 + rs.w);
    int bb = r & 7, p = pbase + (r >> 3);
    *(float4*)&out[((size_t)bb * OUT_PNN + p) * OCC + og] = o4;
  }
}

extern "C" void kernel_launch(void* const* d_in, const int* in_sizes, int n_in,
                              void* d_out, int out_size, void* d_ws, size_t ws_size,
                              hipStream_t stream) {
  const float* in_pc   = (const float*)d_in[0];
  const float* weights = (const float*)d_in[1];
  const float* bias    = (const float*)d_in[2];
  const float* w_w     = (const float*)d_in[3];
  const float* praw    = (const float*)d_in[4];
  const float* wres    = (const float*)d_in[5];
  const int*   nid     = (const int*)d_in[6];
  float* outp = (float*)d_out;

  __hip_bfloat16* ktb = (__hip_bfloat16*)d_ws;
  float* wrt = (float*)((char*)d_ws + 131072);
  float* wwm = (float*)((char*)d_ws + 262144);

  prep_kernel<<<4096, 256, 0, stream>>>(weights, wres, w_w, nid, ktb, wrt, wwm);
  fused6_kernel<<<OUT_PNN / NP, 512, 0, stream>>>(in_pc, bias, praw, nid,
                                                  (const char*)ktb, wrt, wwm, outp);
}